// Round 6
// baseline (888.461 us; speedup 1.0000x reference)
//
#include <hip/hip_runtime.h>
#include <hip/hip_bf16.h>

namespace {

constexpr int B  = 2;
constexpr int S  = 2048;
constexpr int D  = 1024;
constexpr int H  = 16;
constexpr int BH = B * H;           // 32
constexpr float SCALE = 0.125f;     // HD^-0.5
constexpr float THR = 8.0f;         // defer-max threshold (T13)

constexpr int GM = B * S;   // 4096
constexpr int GN = D;       // 1024
constexpr int GK = D;       // 1024

typedef __bf16 bf16x8 __attribute__((ext_vector_type(8)));
typedef float  f32x4  __attribute__((ext_vector_type(4)));
typedef unsigned short u16;
typedef u16 u16x8 __attribute__((ext_vector_type(8)));
typedef u16 u16x4 __attribute__((ext_vector_type(4)));

__device__ __forceinline__ u16 f2bf(float f) {
  union { float f; unsigned u; } v{f};
  unsigned r = v.u + 0x7fffu + ((v.u >> 16) & 1u);   // RNE
  return (u16)(r >> 16);
}
__device__ __forceinline__ float bf2f(u16 u) {
  union { unsigned u; float f; } v{(unsigned)u << 16};
  return v.f;
}

__device__ __forceinline__ f32x4 mfma16(bf16x8 a, bf16x8 b, f32x4 c) {
  return __builtin_amdgcn_mfma_f32_16x16x32_bf16(a, b, c, 0, 0, 0);
}

__device__ __forceinline__ void gload_lds16(const u16* g, u16* l) {
  __builtin_amdgcn_global_load_lds(
      (const __attribute__((address_space(1))) void*)g,
      (__attribute__((address_space(3))) void*)l, 16, 0, 0);
}

// ---------------- fp32 -> bf16 conversion (batched over blockIdx.z) --------
__global__ __launch_bounds__(256) void cvt3_k(
    const float* __restrict__ a, const float* __restrict__ b,
    const float* __restrict__ c, u16* __restrict__ da,
    u16* __restrict__ db, u16* __restrict__ dc)
{
  const float* s = (blockIdx.z == 0) ? a : (blockIdx.z == 1) ? b : c;
  u16* d = (blockIdx.z == 0) ? da : (blockIdx.z == 1) ? db : dc;
  size_t i = ((size_t)blockIdx.x * 256 + threadIdx.x) * 4;
  float4 v = *(const float4*)&s[i];
  u16x4 o = { f2bf(v.x), f2bf(v.y), f2bf(v.z), f2bf(v.w) };
  *(u16x4*)&d[i] = o;
}

__global__ __launch_bounds__(256) void cvt4_k(
    const float* __restrict__ a, const float* __restrict__ b,
    const float* __restrict__ c, const float* __restrict__ e,
    u16* __restrict__ da, u16* __restrict__ db,
    u16* __restrict__ dc, u16* __restrict__ de)
{
  const float* s = (blockIdx.z == 0) ? a : (blockIdx.z == 1) ? b
                 : (blockIdx.z == 2) ? c : e;
  u16* d = (blockIdx.z == 0) ? da : (blockIdx.z == 1) ? db
         : (blockIdx.z == 2) ? dc : de;
  size_t i = ((size_t)blockIdx.x * 256 + threadIdx.x) * 4;
  float4 v = *(const float4*)&s[i];
  u16x4 o = { f2bf(v.x), f2bf(v.y), f2bf(v.z), f2bf(v.w) };
  *(u16x4*)&d[i] = o;
}

// ---------------- bf16 MFMA GEMM, 128x64 tile, BK=64, gload_lds + swizzle --
// C[M,N] = A[M,K] @ W[N,K]^T + bias. 4 waves (2x2), wave = 64x32 out.
// Grid (GN/64, GM/128, NZ). More blocks (512/gemm) -> latency hiding.
template <bool OUTBF, int NZ>
__global__ __launch_bounds__(256) void gemm_k(
    const u16* __restrict__ A0, const u16* __restrict__ A1, const u16* __restrict__ A2,
    const u16* __restrict__ W0, const u16* __restrict__ W1, const u16* __restrict__ W2,
    const float* __restrict__ b0, const float* __restrict__ b1, const float* __restrict__ b2,
    u16* __restrict__ C0, u16* __restrict__ C1, u16* __restrict__ C2,
    float* __restrict__ Cf)
{
  constexpr int BM = 128, BN = 64, BK = 64;
  __shared__ u16 Al[2][BM * BK];   // 2 x 16 KB
  __shared__ u16 Bl[2][BN * BK];   // 2 x 8 KB

  const int z = (NZ > 1) ? blockIdx.z : 0;
  const u16* Ap = (z == 0) ? A0 : (z == 1) ? A1 : A2;
  const u16* Wp = (z == 0) ? W0 : (z == 1) ? W1 : W2;
  const float* bias = (z == 0) ? b0 : (z == 1) ? b1 : b2;
  u16* Cb = (z == 0) ? C0 : (z == 1) ? C1 : C2;

  const int tid  = threadIdx.x;
  const int lane = tid & 63;
  const int w    = tid >> 6;
  const int wr = w >> 1, wc = w & 1;
  const int lg = lane >> 4, ll = lane & 15;
  const int bm = blockIdx.y * BM, bn = blockIdx.x * BN;

  auto STAGE = [&](int buf, int k0) {
#pragma unroll
    for (int i = 0; i < 4; ++i) {
      const int c = i * 256 + tid;
      const int row = c >> 3, cs = c & 7;
      const int dofs = ((cs * 16) ^ ((row & 7) << 4)) >> 1;
      gload_lds16(&Ap[(size_t)(bm + row) * GK + k0 + dofs], &Al[buf][c * 8]);
    }
#pragma unroll
    for (int i = 0; i < 2; ++i) {
      const int c = i * 256 + tid;
      const int row = c >> 3, cs = c & 7;
      const int dofs = ((cs * 16) ^ ((row & 7) << 4)) >> 1;
      gload_lds16(&Wp[(size_t)(bn + row) * GK + k0 + dofs], &Bl[buf][c * 8]);
    }
  };

  f32x4 acc[4][2] = {};

  STAGE(0, 0);
  __syncthreads();

  int cur = 0;
  constexpr int NT = GK / BK;   // 16
  for (int t = 0; t < NT; ++t) {
    if (t + 1 < NT) STAGE(cur ^ 1, (t + 1) * BK);
#pragma unroll
    for (int half = 0; half < 2; ++half) {
      bf16x8 af[4], bfr[2];
#pragma unroll
      for (int mi = 0; mi < 4; ++mi) {
        const int row = wr * 64 + mi * 16 + ll;
        af[mi] = *(const bf16x8*)&Al[cur][row * 64 +
                   (((half * 64 + lg * 16) ^ ((row & 7) << 4)) >> 1)];
      }
#pragma unroll
      for (int ni = 0; ni < 2; ++ni) {
        const int row = wc * 32 + ni * 16 + ll;
        bfr[ni] = *(const bf16x8*)&Bl[cur][row * 64 +
                   (((half * 64 + lg * 16) ^ ((row & 7) << 4)) >> 1)];
      }
#pragma unroll
      for (int mi = 0; mi < 4; ++mi)
#pragma unroll
        for (int ni = 0; ni < 2; ++ni)
          acc[mi][ni] = mfma16(af[mi], bfr[ni], acc[mi][ni]);
    }
    __syncthreads();
    cur ^= 1;
  }

#pragma unroll
  for (int ni = 0; ni < 2; ++ni) {
    const int gcol = bn + wc * 32 + ni * 16 + ll;
    const float bv = bias[gcol];
#pragma unroll
    for (int mi = 0; mi < 4; ++mi) {
      const int grow = bm + wr * 64 + mi * 16 + lg * 4;
#pragma unroll
      for (int r = 0; r < 4; ++r) {
        float v = acc[mi][ni][r] + bv;
        if (OUTBF) Cb[(size_t)(grow + r) * GN + gcol] = f2bf(v);
        else       Cf[(size_t)(grow + r) * GN + gcol] = v;
      }
    }
  }
}

// ---------------- V transpose: Vbf[b,s,h*64+d] -> Vt[(b*H+h)*64+d][s] ------
__global__ __launch_bounds__(256) void transpose_v_k(
    const u16* __restrict__ Vb, u16* __restrict__ Vt)
{
  __shared__ u16 T[64][72];
  const int tid = threadIdx.x;
  const int bh = blockIdx.y, b = bh >> 4, h = bh & 15;
  const int s0 = blockIdx.x * 64;
#pragma unroll
  for (int it = 0; it < 2; ++it) {
    int idx = tid + it * 256;
    int s = idx >> 3, dc = idx & 7;
    *(uint4*)&T[s][dc * 8] =
        *(const uint4*)&Vb[(size_t)(b * S + s0 + s) * D + h * 64 + dc * 8];
  }
  __syncthreads();
#pragma unroll
  for (int it = 0; it < 2; ++it) {
    int idx = tid + it * 256;
    int d = idx >> 3, sc = idx & 7;
    u16x8 o;
#pragma unroll
    for (int jj = 0; jj < 8; ++jj) o[jj] = T[sc * 8 + jj][d];
    *(u16x8*)&Vt[((size_t)bh * 64 + d) * S + s0 + sc * 8] = o;
  }
}

// ---------------- split-KV MFMA flash attention ----------------------------
// grid (S/64, BH, 2 splits). Each block: 64 q-rows (4 waves x 16), kv range
// [split*1024, split*1024+1024) in 16 tiles of 64. Defer-max fast path: no
// cross-lane shuffles unless per-lane max exceeds m+THR. Unnormalized O
// (bf16) + (m,l) written per split; merged by merge_k.
__global__ __launch_bounds__(256, 6) void attn_split_k(
    const u16* __restrict__ Qb, const u16* __restrict__ Kb,
    const u16* __restrict__ Vt, const float* __restrict__ biasS,
    const float* __restrict__ lamp, u16* __restrict__ Opart,
    float2* __restrict__ Ml)
{
  __shared__ u16 Kl[2][64 * 64];       // 2 x 8 KB, swizzled rows
  __shared__ __bf16 Pl[4][16][72];     // per-wave P, row stride 144B

  const int tid  = threadIdx.x;
  const int lane = tid & 63;
  const int w    = tid >> 6;
  const int lg = lane >> 4, ll = lane & 15;
  const int bh = blockIdx.y, b = bh >> 4, h = bh & 15;
  const int qw = blockIdx.x * 64 + w * 16;
  const int split = blockIdx.z;
  const int kvbase = split * (S / 2);  // 0 or 1024
  const float lam = lamp[0];

  bf16x8 aQ[2];
  {
    const u16* qrow = &Qb[(size_t)(b * S + qw + ll) * D + h * 64];
    aQ[0] = *(const bf16x8*)&qrow[lg * 8];
    aQ[1] = *(const bf16x8*)&qrow[32 + lg * 8];
  }

  const u16* Kbase = &Kb[(size_t)(b * S + kvbase) * D + h * 64];
  const u16* Vbase = &Vt[(size_t)bh * 64 * S + kvbase];
  const float* Bb  = &biasS[((size_t)b * S + qw + lg * 4) * S + kvbase];

  auto STAGE_K = [&](int buf, int k0) {
#pragma unroll
    for (int i = 0; i < 2; ++i) {
      const int c   = (w * 2 + i) * 64 + lane;
      const int row = c >> 3, cs = c & 7;
      const int dofs = ((cs * 16) ^ ((row & 7) << 4)) >> 1;
      gload_lds16(&Kbase[(size_t)(k0 + row) * D + dofs],
                  &Kl[buf][(w * 2 + i) * 512]);
    }
  };

  f32x4 accO[4] = {};
  float m_r[4], l_r[4];
#pragma unroll
  for (int r = 0; r < 4; ++r) { m_r[r] = -1e30f; l_r[r] = 0.f; }

  float bc[4][4];
  STAGE_K(0, 0);
#pragma unroll
  for (int r = 0; r < 4; ++r)
#pragma unroll
    for (int kf = 0; kf < 4; ++kf)
      bc[r][kf] = Bb[(size_t)r * S + kf * 16 + ll];
  __syncthreads();                     // buf0 staged

  int cur = 0;
  constexpr int NT = (S / 2) / 64;     // 16
  for (int t = 0; t < NT; ++t) {
    const int k0 = t * 64;
    if (t + 1 < NT) STAGE_K(cur ^ 1, k0 + 64);

    // V fragments issued early (used after softmax)
    bf16x8 v0[4], v1[4];
#pragma unroll
    for (int nf = 0; nf < 4; ++nf) {
      const u16* vrow = &Vbase[(size_t)(nf * 16 + ll) * S + k0];
      v0[nf] = *(const bf16x8*)&vrow[lg * 8];
      v1[nf] = *(const bf16x8*)&vrow[32 + lg * 8];
    }
    // bias prefetch for next tile
    float bnx[4][4];
    if (t + 1 < NT) {
#pragma unroll
      for (int r = 0; r < 4; ++r)
#pragma unroll
        for (int kf = 0; kf < 4; ++kf)
          bnx[r][kf] = Bb[(size_t)r * S + k0 + 64 + kf * 16 + ll];
    }

    // ---- QK^T from LDS (swizzled) ----
    f32x4 sf[4];
#pragma unroll
    for (int kf = 0; kf < 4; ++kf) {
      const int row = kf * 16 + ll;
      const u16* kr = &Kl[cur][row * 64];
      bf16x8 kb0 = *(const bf16x8*)&kr[((lg * 16) ^ ((row & 7) << 4)) >> 1];
      bf16x8 kb1 = *(const bf16x8*)&kr[((64 + lg * 16) ^ ((row & 7) << 4)) >> 1];
      f32x4 t4 = {0.f, 0.f, 0.f, 0.f};
      t4 = mfma16(aQ[0], kb0, t4);
      t4 = mfma16(aQ[1], kb1, t4);
#pragma unroll
      for (int r = 0; r < 4; ++r)
        t4[r] = t4[r] * SCALE + lam * bc[r][kf];
      sf[kf] = t4;
    }

    // ---- defer-max online softmax (T13): fast path has NO shuffles ----
    float pm[4];
#pragma unroll
    for (int r = 0; r < 4; ++r)
      pm[r] = fmaxf(fmaxf(sf[0][r], sf[1][r]), fmaxf(sf[2][r], sf[3][r]));
    float ex = fmaxf(fmaxf(pm[0] - m_r[0], pm[1] - m_r[1]),
                     fmaxf(pm[2] - m_r[2], pm[3] - m_r[3]));
    if (__any(ex > THR)) {             // rare after first tile
#pragma unroll
      for (int r = 0; r < 4; ++r) {
        float tmx = pm[r];
        tmx = fmaxf(tmx, __shfl_xor(tmx, 1));
        tmx = fmaxf(tmx, __shfl_xor(tmx, 2));
        tmx = fmaxf(tmx, __shfl_xor(tmx, 4));
        tmx = fmaxf(tmx, __shfl_xor(tmx, 8));
        float nm = fmaxf(m_r[r], tmx);
        float cf = __expf(m_r[r] - nm);
        m_r[r] = nm;
        l_r[r] *= cf;
#pragma unroll
        for (int nf = 0; nf < 4; ++nf) accO[nf][r] *= cf;
      }
    }
#pragma unroll
    for (int r = 0; r < 4; ++r) {
      float ps = 0.f;
#pragma unroll
      for (int kf = 0; kf < 4; ++kf) {
        float p = __expf(sf[kf][r] - m_r[r]);
        Pl[w][lg * 4 + r][kf * 16 + ll] = (__bf16)p;
        ps += p;
      }
      l_r[r] += ps;                    // per-lane partial l
    }

    // ---- PV ----
    bf16x8 aP0 = *(const bf16x8*)&Pl[w][ll][lg * 8];
    bf16x8 aP1 = *(const bf16x8*)&Pl[w][ll][32 + lg * 8];
#pragma unroll
    for (int nf = 0; nf < 4; ++nf) {
      accO[nf] = mfma16(aP0, v0[nf], accO[nf]);
      accO[nf] = mfma16(aP1, v1[nf], accO[nf]);
    }

    if (t + 1 < NT) {
#pragma unroll
      for (int r = 0; r < 4; ++r)
#pragma unroll
        for (int kf = 0; kf < 4; ++kf) bc[r][kf] = bnx[r][kf];
    }
    __syncthreads();                   // next K buffer staged
    cur ^= 1;
  }

  // reduce per-lane partial l across the 16-lane row groups (once)
#pragma unroll
  for (int r = 0; r < 4; ++r) {
    float tl = l_r[r];
    tl += __shfl_xor(tl, 1);
    tl += __shfl_xor(tl, 2);
    tl += __shfl_xor(tl, 4);
    tl += __shfl_xor(tl, 8);
    l_r[r] = tl;
  }

  u16* Op = Opart + (size_t)split * ((size_t)BH * S * 64);
  float2* Mlp = Ml + (size_t)split * ((size_t)BH * S);
  if (ll == 0) {
#pragma unroll
    for (int r = 0; r < 4; ++r) {
      float2 v; v.x = m_r[r]; v.y = l_r[r];
      Mlp[(size_t)bh * S + qw + lg * 4 + r] = v;
    }
  }
#pragma unroll
  for (int nf = 0; nf < 4; ++nf)
#pragma unroll
    for (int r = 0; r < 4; ++r)
      Op[((size_t)bh * S + qw + lg * 4 + r) * 64 + nf * 16 + ll] =
          f2bf(accO[nf][r]);
}

// ---------------- merge partial attention results --------------------------
// row = bh*S + q (65536 rows); 8 threads/row, 8 d-elems each.
__global__ __launch_bounds__(256) void merge_k(
    const u16* __restrict__ Opart, const float2* __restrict__ Ml,
    u16* __restrict__ Obf)
{
  const int tid = threadIdx.x;
  const size_t row = (size_t)blockIdx.x * 32 + (tid >> 3);
  const int dc = (tid & 7) * 8;
  const float2 ml0 = Ml[row];
  const float2 ml1 = Ml[(size_t)BH * S + row];
  const float m = fmaxf(ml0.x, ml1.x);
  float c0 = __expf(ml0.x - m), c1 = __expf(ml1.x - m);
  const float inv = 1.0f / (c0 * ml0.y + c1 * ml1.y);
  c0 *= inv; c1 *= inv;
  u16x8 a = *(const u16x8*)&Opart[row * 64 + dc];
  u16x8 bq = *(const u16x8*)&Opart[(size_t)BH * S * 64 + row * 64 + dc];
  u16x8 o;
#pragma unroll
  for (int j = 0; j < 8; ++j)
    o[j] = f2bf(c0 * bf2f(a[j]) + c1 * bf2f(bq[j]));
  const int bh = (int)(row >> 11), q = (int)(row & 2047);
  *(u16x8*)&Obf[((size_t)((bh >> 4) * S + q)) * D + (bh & 15) * 64 + dc] = o;
}

}  // namespace

extern "C" void kernel_launch(void* const* d_in, const int* in_sizes, int n_in,
                              void* d_out, int out_size, void* d_ws, size_t ws_size,
                              hipStream_t stream)
{
  const float* query = (const float*)d_in[0];
  const float* key   = (const float*)d_in[1];
  const float* value = (const float*)d_in[2];
  const float* biasS = (const float*)d_in[3];
  const float* Wq = (const float*)d_in[4];
  const float* bq = (const float*)d_in[5];
  const float* Wk = (const float*)d_in[6];
  const float* bk = (const float*)d_in[7];
  const float* Wv = (const float*)d_in[8];
  const float* bv = (const float*)d_in[9];
  const float* Wo = (const float*)d_in[10];
  const float* bo = (const float*)d_in[11];
  const float* lam = (const float*)d_in[12];
  float* out = (float*)d_out;

  // ws layout (48 MB), regions reused once dead:
  //  [0:8]   Xq      -> Opart split0 (attn)
  //  [8:16]  Xk      -> Opart split1
  //  [16:24] Xv      -> Obf (merge out)
  //  [24:32] WqB,WkB,WvB,WoB (2 MB each)
  //  [32:40] Qbf
  //  [40:48] Kbf
  // d_out (16 MB): [0:8] Vbf (until transpose) -> Ml [0:1] (attn/merge);
  //                [8:16] Vt (until attn end); final GEMM overwrites all.
  char* ws = (char*)d_ws;
  const size_t MB = 1024 * 1024;
  u16* Xq  = (u16*)(ws + 0 * MB);
  u16* Xk  = (u16*)(ws + 8 * MB);
  u16* Xv  = (u16*)(ws + 16 * MB);
  u16* WqB = (u16*)(ws + 24 * MB);
  u16* WkB = (u16*)(ws + 26 * MB);
  u16* WvB = (u16*)(ws + 28 * MB);
  u16* WoB = (u16*)(ws + 30 * MB);
  u16* Qbf = (u16*)(ws + 32 * MB);
  u16* Kbf = (u16*)(ws + 40 * MB);
  u16* Opart = (u16*)ws;                       // [2][BH*S*64] bf16, 16 MB
  u16* Obf   = (u16*)(ws + 16 * MB);           // 8 MB (over Xv)
  u16* Vbf = (u16*)d_out;                      // 8 MB
  u16* Vt  = (u16*)d_out + (size_t)4 * MB;     // 8 MB (elems: 4M u16)
  float2* Ml = (float2*)d_out;                 // 1 MB (after Vbf dead)

  // 1) fp32 -> bf16
  cvt3_k<<<dim3(4096, 1, 3), 256, 0, stream>>>(query, key, value, Xq, Xk, Xv);
  cvt4_k<<<dim3(1024, 1, 4), 256, 0, stream>>>(Wq, Wk, Wv, Wo, WqB, WkB, WvB, WoB);

  // 2) fused Q,K,V projections (z=3; 1536 blocks)
  dim3 pgrid(GN / 64, GM / 128, 3);
  gemm_k<true, 3><<<pgrid, 256, 0, stream>>>(
      Xq, Xk, Xv, WqB, WkB, WvB, bq, bk, bv, Qbf, Kbf, Vbf, nullptr);

  // 3) V transpose
  transpose_v_k<<<dim3(S / 64, B * H), 256, 0, stream>>>(Vbf, Vt);

  // 4) split-KV flash attention (2048 blocks)
  attn_split_k<<<dim3(S / 64, BH, 2), 256, 0, stream>>>(
      Qbf, Kbf, Vt, biasS, lam, Opart, Ml);

  // 5) merge partials
  merge_k<<<dim3(BH * S / 32), 256, 0, stream>>>(Opart, Ml, Obf);

  // 6) output projection (fp32 out)
  dim3 ogrid(GN / 64, GM / 128, 1);
  gemm_k<false, 1><<<ogrid, 256, 0, stream>>>(
      Obf, nullptr, nullptr, WoB, nullptr, nullptr, bo, nullptr, nullptr,
      nullptr, nullptr, nullptr, out);
}

// Round 7
// 405.325 us; speedup vs baseline: 2.1920x; 2.1920x over previous
//
#include <hip/hip_runtime.h>
#include <hip/hip_bf16.h>

namespace {

constexpr int B  = 2;
constexpr int S  = 2048;
constexpr int D  = 1024;
constexpr int H  = 16;
constexpr int BH = B * H;           // 32
constexpr float SCALE = 0.125f;     // HD^-0.5
constexpr float THR = 8.0f;         // defer-max threshold (T13)

constexpr int GM = B * S;   // 4096
constexpr int GN = D;       // 1024
constexpr int GK = D;       // 1024

typedef __bf16 bf16x8 __attribute__((ext_vector_type(8)));
typedef float  f32x4  __attribute__((ext_vector_type(4)));
typedef unsigned short u16;
typedef u16 u16x8 __attribute__((ext_vector_type(8)));
typedef u16 u16x4 __attribute__((ext_vector_type(4)));

__device__ __forceinline__ u16 f2bf(float f) {
  union { float f; unsigned u; } v{f};
  unsigned r = v.u + 0x7fffu + ((v.u >> 16) & 1u);   // RNE
  return (u16)(r >> 16);
}
__device__ __forceinline__ float bf2f(u16 u) {
  union { unsigned u; float f; } v{(unsigned)u << 16};
  return v.f;
}

__device__ __forceinline__ f32x4 mfma16(bf16x8 a, bf16x8 b, f32x4 c) {
  return __builtin_amdgcn_mfma_f32_16x16x32_bf16(a, b, c, 0, 0, 0);
}

__device__ __forceinline__ void gload_lds16(const u16* g, u16* l) {
  __builtin_amdgcn_global_load_lds(
      (const __attribute__((address_space(1))) void*)g,
      (__attribute__((address_space(3))) void*)l, 16, 0, 0);
}

// ---------------- fp32 -> bf16 conversion (batched over blockIdx.z) --------
__global__ __launch_bounds__(256) void cvt3_k(
    const float* __restrict__ a, const float* __restrict__ b,
    const float* __restrict__ c, u16* __restrict__ da,
    u16* __restrict__ db, u16* __restrict__ dc)
{
  const float* s = (blockIdx.z == 0) ? a : (blockIdx.z == 1) ? b : c;
  u16* d = (blockIdx.z == 0) ? da : (blockIdx.z == 1) ? db : dc;
  size_t i = ((size_t)blockIdx.x * 256 + threadIdx.x) * 4;
  float4 v = *(const float4*)&s[i];
  u16x4 o = { f2bf(v.x), f2bf(v.y), f2bf(v.z), f2bf(v.w) };
  *(u16x4*)&d[i] = o;
}

__global__ __launch_bounds__(256) void cvt4_k(
    const float* __restrict__ a, const float* __restrict__ b,
    const float* __restrict__ c, const float* __restrict__ e,
    u16* __restrict__ da, u16* __restrict__ db,
    u16* __restrict__ dc, u16* __restrict__ de)
{
  const float* s = (blockIdx.z == 0) ? a : (blockIdx.z == 1) ? b
                 : (blockIdx.z == 2) ? c : e;
  u16* d = (blockIdx.z == 0) ? da : (blockIdx.z == 1) ? db
         : (blockIdx.z == 2) ? dc : de;
  size_t i = ((size_t)blockIdx.x * 256 + threadIdx.x) * 4;
  float4 v = *(const float4*)&s[i];
  u16x4 o = { f2bf(v.x), f2bf(v.y), f2bf(v.z), f2bf(v.w) };
  *(u16x4*)&d[i] = o;
}

// ---------------- bf16 MFMA GEMM, 128x64 tile, BK=64, gload_lds + swizzle --
// C[M,N] = A[M,K] @ W[N,K]^T + bias. 4 waves (2x2), wave = 64x32 out.
// Grid (GN/64, GM/128, NZ). More blocks (512/gemm) -> latency hiding.
template <bool OUTBF, int NZ>
__global__ __launch_bounds__(256) void gemm_k(
    const u16* __restrict__ A0, const u16* __restrict__ A1, const u16* __restrict__ A2,
    const u16* __restrict__ W0, const u16* __restrict__ W1, const u16* __restrict__ W2,
    const float* __restrict__ b0, const float* __restrict__ b1, const float* __restrict__ b2,
    u16* __restrict__ C0, u16* __restrict__ C1, u16* __restrict__ C2,
    float* __restrict__ Cf)
{
  constexpr int BM = 128, BN = 64, BK = 64;
  __shared__ u16 Al[2][BM * BK];   // 2 x 16 KB
  __shared__ u16 Bl[2][BN * BK];   // 2 x 8 KB

  const int z = (NZ > 1) ? blockIdx.z : 0;
  const u16* Ap = (z == 0) ? A0 : (z == 1) ? A1 : A2;
  const u16* Wp = (z == 0) ? W0 : (z == 1) ? W1 : W2;
  const float* bias = (z == 0) ? b0 : (z == 1) ? b1 : b2;
  u16* Cb = (z == 0) ? C0 : (z == 1) ? C1 : C2;

  const int tid  = threadIdx.x;
  const int lane = tid & 63;
  const int w    = tid >> 6;
  const int wr = w >> 1, wc = w & 1;
  const int lg = lane >> 4, ll = lane & 15;
  const int bm = blockIdx.y * BM, bn = blockIdx.x * BN;

  auto STAGE = [&](int buf, int k0) {
#pragma unroll
    for (int i = 0; i < 4; ++i) {
      const int c = i * 256 + tid;
      const int row = c >> 3, cs = c & 7;
      const int dofs = ((cs * 16) ^ ((row & 7) << 4)) >> 1;
      gload_lds16(&Ap[(size_t)(bm + row) * GK + k0 + dofs], &Al[buf][c * 8]);
    }
#pragma unroll
    for (int i = 0; i < 2; ++i) {
      const int c = i * 256 + tid;
      const int row = c >> 3, cs = c & 7;
      const int dofs = ((cs * 16) ^ ((row & 7) << 4)) >> 1;
      gload_lds16(&Wp[(size_t)(bn + row) * GK + k0 + dofs], &Bl[buf][c * 8]);
    }
  };

  f32x4 acc[4][2] = {};

  STAGE(0, 0);
  __syncthreads();

  int cur = 0;
  constexpr int NT = GK / BK;   // 16
  for (int t = 0; t < NT; ++t) {
    if (t + 1 < NT) STAGE(cur ^ 1, (t + 1) * BK);
#pragma unroll
    for (int half = 0; half < 2; ++half) {
      bf16x8 af[4], bfr[2];
#pragma unroll
      for (int mi = 0; mi < 4; ++mi) {
        const int row = wr * 64 + mi * 16 + ll;
        af[mi] = *(const bf16x8*)&Al[cur][row * 64 +
                   (((half * 64 + lg * 16) ^ ((row & 7) << 4)) >> 1)];
      }
#pragma unroll
      for (int ni = 0; ni < 2; ++ni) {
        const int row = wc * 32 + ni * 16 + ll;
        bfr[ni] = *(const bf16x8*)&Bl[cur][row * 64 +
                   (((half * 64 + lg * 16) ^ ((row & 7) << 4)) >> 1)];
      }
#pragma unroll
      for (int mi = 0; mi < 4; ++mi)
#pragma unroll
        for (int ni = 0; ni < 2; ++ni)
          acc[mi][ni] = mfma16(af[mi], bfr[ni], acc[mi][ni]);
    }
    __syncthreads();
    cur ^= 1;
  }

#pragma unroll
  for (int ni = 0; ni < 2; ++ni) {
    const int gcol = bn + wc * 32 + ni * 16 + ll;
    const float bv = bias[gcol];
#pragma unroll
    for (int mi = 0; mi < 4; ++mi) {
      const int grow = bm + wr * 64 + mi * 16 + lg * 4;
#pragma unroll
      for (int r = 0; r < 4; ++r) {
        float v = acc[mi][ni][r] + bv;
        if (OUTBF) Cb[(size_t)(grow + r) * GN + gcol] = f2bf(v);
        else       Cf[(size_t)(grow + r) * GN + gcol] = v;
      }
    }
  }
}

// ---------------- V transpose: Vbf[b,s,h*64+d] -> Vt[(b*H+h)*64+d][s] ------
__global__ __launch_bounds__(256) void transpose_v_k(
    const u16* __restrict__ Vb, u16* __restrict__ Vt)
{
  __shared__ u16 T[64][72];
  const int tid = threadIdx.x;
  const int bh = blockIdx.y, b = bh >> 4, h = bh & 15;
  const int s0 = blockIdx.x * 64;
#pragma unroll
  for (int it = 0; it < 2; ++it) {
    int idx = tid + it * 256;
    int s = idx >> 3, dc = idx & 7;
    *(uint4*)&T[s][dc * 8] =
        *(const uint4*)&Vb[(size_t)(b * S + s0 + s) * D + h * 64 + dc * 8];
  }
  __syncthreads();
#pragma unroll
  for (int it = 0; it < 2; ++it) {
    int idx = tid + it * 256;
    int d = idx >> 3, sc = idx & 7;
    u16x8 o;
#pragma unroll
    for (int jj = 0; jj < 8; ++jj) o[jj] = T[sc * 8 + jj][d];
    *(u16x8*)&Vt[((size_t)bh * 64 + d) * S + s0 + sc * 8] = o;
  }
}

// ---------------- split-KV MFMA flash attention ----------------------------
// grid (S/64, BH, 2 splits). Each block: 64 q-rows (4 waves x 16), kv range
// [split*1024, split*1024+1024) in 16 tiles of 64. Defer-max fast path: no
// cross-lane shuffles unless per-lane max exceeds m+THR. Unnormalized O
// (bf16) + (m,l) written per split; merged by merge_k.
// NOTE: plain __launch_bounds__(256) — round 6's (256,6) forced VGPR=40 under
// the ~56-reg live set and spilled to scratch (FETCH+WRITE exploded to 2.5GB).
// Occupancy is LDS-capped at 6 blocks/CU; let the allocator breathe.
__global__ __launch_bounds__(256) void attn_split_k(
    const u16* __restrict__ Qb, const u16* __restrict__ Kb,
    const u16* __restrict__ Vt, const float* __restrict__ biasS,
    const float* __restrict__ lamp, u16* __restrict__ Opart,
    float2* __restrict__ Ml)
{
  __shared__ u16 Kl[2][64 * 64];       // 2 x 8 KB, swizzled rows
  __shared__ __bf16 Pl[4][16][72];     // per-wave P, row stride 144B

  const int tid  = threadIdx.x;
  const int lane = tid & 63;
  const int w    = tid >> 6;
  const int lg = lane >> 4, ll = lane & 15;
  const int bh = blockIdx.y, b = bh >> 4, h = bh & 15;
  const int qw = blockIdx.x * 64 + w * 16;
  const int split = blockIdx.z;
  const int kvbase = split * (S / 2);  // 0 or 1024
  const float lam = lamp[0];

  bf16x8 aQ[2];
  {
    const u16* qrow = &Qb[(size_t)(b * S + qw + ll) * D + h * 64];
    aQ[0] = *(const bf16x8*)&qrow[lg * 8];
    aQ[1] = *(const bf16x8*)&qrow[32 + lg * 8];
  }

  const u16* Kbase = &Kb[(size_t)(b * S + kvbase) * D + h * 64];
  const u16* Vbase = &Vt[(size_t)bh * 64 * S + kvbase];
  const float* Bb  = &biasS[((size_t)b * S + qw + lg * 4) * S + kvbase];

  auto STAGE_K = [&](int buf, int k0) {
#pragma unroll
    for (int i = 0; i < 2; ++i) {
      const int c   = (w * 2 + i) * 64 + lane;
      const int row = c >> 3, cs = c & 7;
      const int dofs = ((cs * 16) ^ ((row & 7) << 4)) >> 1;
      gload_lds16(&Kbase[(size_t)(k0 + row) * D + dofs],
                  &Kl[buf][(w * 2 + i) * 512]);
    }
  };

  f32x4 accO[4] = {};
  float m_r[4], l_r[4];
#pragma unroll
  for (int r = 0; r < 4; ++r) { m_r[r] = -1e30f; l_r[r] = 0.f; }

  float bc[4][4];
  STAGE_K(0, 0);
#pragma unroll
  for (int r = 0; r < 4; ++r)
#pragma unroll
    for (int kf = 0; kf < 4; ++kf)
      bc[r][kf] = Bb[(size_t)r * S + kf * 16 + ll];
  __syncthreads();                     // buf0 staged

  int cur = 0;
  constexpr int NT = (S / 2) / 64;     // 16
  for (int t = 0; t < NT; ++t) {
    const int k0 = t * 64;
    if (t + 1 < NT) STAGE_K(cur ^ 1, k0 + 64);

    // V fragments issued early (used after softmax)
    bf16x8 v0[4], v1[4];
#pragma unroll
    for (int nf = 0; nf < 4; ++nf) {
      const u16* vrow = &Vbase[(size_t)(nf * 16 + ll) * S + k0];
      v0[nf] = *(const bf16x8*)&vrow[lg * 8];
      v1[nf] = *(const bf16x8*)&vrow[32 + lg * 8];
    }
    // bias prefetch for next tile
    float bnx[4][4];
    if (t + 1 < NT) {
#pragma unroll
      for (int r = 0; r < 4; ++r)
#pragma unroll
        for (int kf = 0; kf < 4; ++kf)
          bnx[r][kf] = Bb[(size_t)r * S + k0 + 64 + kf * 16 + ll];
    }

    // ---- QK^T from LDS (swizzled) ----
    f32x4 sf[4];
#pragma unroll
    for (int kf = 0; kf < 4; ++kf) {
      const int row = kf * 16 + ll;
      const u16* kr = &Kl[cur][row * 64];
      bf16x8 kb0 = *(const bf16x8*)&kr[((lg * 16) ^ ((row & 7) << 4)) >> 1];
      bf16x8 kb1 = *(const bf16x8*)&kr[((64 + lg * 16) ^ ((row & 7) << 4)) >> 1];
      f32x4 t4 = {0.f, 0.f, 0.f, 0.f};
      t4 = mfma16(aQ[0], kb0, t4);
      t4 = mfma16(aQ[1], kb1, t4);
#pragma unroll
      for (int r = 0; r < 4; ++r)
        t4[r] = t4[r] * SCALE + lam * bc[r][kf];
      sf[kf] = t4;
    }

    // ---- defer-max online softmax (T13): fast path has NO shuffles ----
    float pm[4];
#pragma unroll
    for (int r = 0; r < 4; ++r)
      pm[r] = fmaxf(fmaxf(sf[0][r], sf[1][r]), fmaxf(sf[2][r], sf[3][r]));
    float ex = fmaxf(fmaxf(pm[0] - m_r[0], pm[1] - m_r[1]),
                     fmaxf(pm[2] - m_r[2], pm[3] - m_r[3]));
    if (__any(ex > THR)) {             // rare after first tile
#pragma unroll
      for (int r = 0; r < 4; ++r) {
        float tmx = pm[r];
        tmx = fmaxf(tmx, __shfl_xor(tmx, 1));
        tmx = fmaxf(tmx, __shfl_xor(tmx, 2));
        tmx = fmaxf(tmx, __shfl_xor(tmx, 4));
        tmx = fmaxf(tmx, __shfl_xor(tmx, 8));
        float nm = fmaxf(m_r[r], tmx);
        float cf = __expf(m_r[r] - nm);
        m_r[r] = nm;
        l_r[r] *= cf;
#pragma unroll
        for (int nf = 0; nf < 4; ++nf) accO[nf][r] *= cf;
      }
    }
#pragma unroll
    for (int r = 0; r < 4; ++r) {
      float ps = 0.f;
#pragma unroll
      for (int kf = 0; kf < 4; ++kf) {
        float p = __expf(sf[kf][r] - m_r[r]);
        Pl[w][lg * 4 + r][kf * 16 + ll] = (__bf16)p;
        ps += p;
      }
      l_r[r] += ps;                    // per-lane partial l
    }

    // ---- PV ----
    bf16x8 aP0 = *(const bf16x8*)&Pl[w][ll][lg * 8];
    bf16x8 aP1 = *(const bf16x8*)&Pl[w][ll][32 + lg * 8];
#pragma unroll
    for (int nf = 0; nf < 4; ++nf) {
      accO[nf] = mfma16(aP0, v0[nf], accO[nf]);
      accO[nf] = mfma16(aP1, v1[nf], accO[nf]);
    }

    if (t + 1 < NT) {
#pragma unroll
      for (int r = 0; r < 4; ++r)
#pragma unroll
        for (int kf = 0; kf < 4; ++kf) bc[r][kf] = bnx[r][kf];
    }
    __syncthreads();                   // next K buffer staged
    cur ^= 1;
  }

  // reduce per-lane partial l across the 16-lane row groups (once)
#pragma unroll
  for (int r = 0; r < 4; ++r) {
    float tl = l_r[r];
    tl += __shfl_xor(tl, 1);
    tl += __shfl_xor(tl, 2);
    tl += __shfl_xor(tl, 4);
    tl += __shfl_xor(tl, 8);
    l_r[r] = tl;
  }

  u16* Op = Opart + (size_t)split * ((size_t)BH * S * 64);
  float2* Mlp = Ml + (size_t)split * ((size_t)BH * S);
  if (ll == 0) {
#pragma unroll
    for (int r = 0; r < 4; ++r) {
      float2 v; v.x = m_r[r]; v.y = l_r[r];
      Mlp[(size_t)bh * S + qw + lg * 4 + r] = v;
    }
  }
#pragma unroll
  for (int nf = 0; nf < 4; ++nf)
#pragma unroll
    for (int r = 0; r < 4; ++r)
      Op[((size_t)bh * S + qw + lg * 4 + r) * 64 + nf * 16 + ll] =
          f2bf(accO[nf][r]);
}

// ---------------- merge partial attention results --------------------------
// row = bh*S + q (65536 rows); 8 threads/row, 8 d-elems each.
__global__ __launch_bounds__(256) void merge_k(
    const u16* __restrict__ Opart, const float2* __restrict__ Ml,
    u16* __restrict__ Obf)
{
  const int tid = threadIdx.x;
  const size_t row = (size_t)blockIdx.x * 32 + (tid >> 3);
  const int dc = (tid & 7) * 8;
  const float2 ml0 = Ml[row];
  const float2 ml1 = Ml[(size_t)BH * S + row];
  const float m = fmaxf(ml0.x, ml1.x);
  float c0 = __expf(ml0.x - m), c1 = __expf(ml1.x - m);
  const float inv = 1.0f / (c0 * ml0.y + c1 * ml1.y);
  c0 *= inv; c1 *= inv;
  u16x8 a = *(const u16x8*)&Opart[row * 64 + dc];
  u16x8 bq = *(const u16x8*)&Opart[(size_t)BH * S * 64 + row * 64 + dc];
  u16x8 o;
#pragma unroll
  for (int j = 0; j < 8; ++j)
    o[j] = f2bf(c0 * bf2f(a[j]) + c1 * bf2f(bq[j]));
  const int bh = (int)(row >> 11), q = (int)(row & 2047);
  *(u16x8*)&Obf[((size_t)((bh >> 4) * S + q)) * D + (bh & 15) * 64 + dc] = o;
}

}  // namespace

extern "C" void kernel_launch(void* const* d_in, const int* in_sizes, int n_in,
                              void* d_out, int out_size, void* d_ws, size_t ws_size,
                              hipStream_t stream)
{
  const float* query = (const float*)d_in[0];
  const float* key   = (const float*)d_in[1];
  const float* value = (const float*)d_in[2];
  const float* biasS = (const float*)d_in[3];
  const float* Wq = (const float*)d_in[4];
  const float* bq = (const float*)d_in[5];
  const float* Wk = (const float*)d_in[6];
  const float* bk = (const float*)d_in[7];
  const float* Wv = (const float*)d_in[8];
  const float* bv = (const float*)d_in[9];
  const float* Wo = (const float*)d_in[10];
  const float* bo = (const float*)d_in[11];
  const float* lam = (const float*)d_in[12];
  float* out = (float*)d_out;

  // ws layout (48 MB), regions reused once dead:
  //  [0:8]   Xq      -> Opart split0 (attn)
  //  [8:16]  Xk      -> Opart split1
  //  [16:24] Xv      -> Obf (merge out)
  //  [24:32] WqB,WkB,WvB,WoB (2 MB each)
  //  [32:40] Qbf
  //  [40:48] Kbf
  // d_out (16 MB): [0:8] Vbf (until transpose) -> Ml [0:1] (attn/merge);
  //                [8:16] Vt (until attn end); final GEMM overwrites all.
  char* ws = (char*)d_ws;
  const size_t MB = 1024 * 1024;
  u16* Xq  = (u16*)(ws + 0 * MB);
  u16* Xk  = (u16*)(ws + 8 * MB);
  u16* Xv  = (u16*)(ws + 16 * MB);
  u16* WqB = (u16*)(ws + 24 * MB);
  u16* WkB = (u16*)(ws + 26 * MB);
  u16* WvB = (u16*)(ws + 28 * MB);
  u16* WoB = (u16*)(ws + 30 * MB);
  u16* Qbf = (u16*)(ws + 32 * MB);
  u16* Kbf = (u16*)(ws + 40 * MB);
  u16* Opart = (u16*)ws;                       // [2][BH*S*64] bf16, 16 MB
  u16* Obf   = (u16*)(ws + 16 * MB);           // 8 MB (over Xv)
  u16* Vbf = (u16*)d_out;                      // 8 MB
  u16* Vt  = (u16*)d_out + (size_t)4 * MB;     // 8 MB (elems: 4M u16)
  float2* Ml = (float2*)d_out;                 // 1 MB (after Vbf dead)

  // 1) fp32 -> bf16
  cvt3_k<<<dim3(4096, 1, 3), 256, 0, stream>>>(query, key, value, Xq, Xk, Xv);
  cvt4_k<<<dim3(1024, 1, 4), 256, 0, stream>>>(Wq, Wk, Wv, Wo, WqB, WkB, WvB, WoB);

  // 2) fused Q,K,V projections (z=3; 1536 blocks)
  dim3 pgrid(GN / 64, GM / 128, 3);
  gemm_k<true, 3><<<pgrid, 256, 0, stream>>>(
      Xq, Xk, Xv, WqB, WkB, WvB, bq, bk, bv, Qbf, Kbf, Vbf, nullptr);

  // 3) V transpose
  transpose_v_k<<<dim3(S / 64, B * H), 256, 0, stream>>>(Vbf, Vt);

  // 4) split-KV flash attention (2048 blocks)
  attn_split_k<<<dim3(S / 64, BH, 2), 256, 0, stream>>>(
      Qbf, Kbf, Vt, biasS, lam, Opart, Ml);

  // 5) merge partials
  merge_k<<<dim3(BH * S / 32), 256, 0, stream>>>(Opart, Ml, Obf);

  // 6) output projection (fp32 out)
  dim3 ogrid(GN / 64, GM / 128, 1);
  gemm_k<false, 1><<<ogrid, 256, 0, stream>>>(
      Obf, nullptr, nullptr, WoB, nullptr, nullptr, bo, nullptr, nullptr,
      nullptr, nullptr, nullptr, out);
}

// Round 8
// 387.577 us; speedup vs baseline: 2.2923x; 1.0458x over previous
//
#include <hip/hip_runtime.h>
#include <hip/hip_bf16.h>

namespace {

constexpr int B  = 2;
constexpr int S  = 2048;
constexpr int D  = 1024;
constexpr int H  = 16;
constexpr int BH = B * H;           // 32
constexpr float SCALE = 0.125f;     // HD^-0.5
constexpr float LOG2E = 1.44269504f;
constexpr float SL2   = SCALE * LOG2E;   // score -> log2 domain
constexpr float THR2  = 8.0f * LOG2E;    // defer-max threshold in log2 domain

constexpr int GM = B * S;   // 4096
constexpr int GN = D;       // 1024
constexpr int GK = D;       // 1024

typedef __bf16 bf16x8 __attribute__((ext_vector_type(8)));
typedef float  f32x4  __attribute__((ext_vector_type(4)));
typedef unsigned short u16;
typedef u16 u16x8 __attribute__((ext_vector_type(8)));
typedef u16 u16x4 __attribute__((ext_vector_type(4)));

__device__ __forceinline__ u16 f2bf(float f) {
  union { float f; unsigned u; } v{f};
  unsigned r = v.u + 0x7fffu + ((v.u >> 16) & 1u);   // RNE
  return (u16)(r >> 16);
}
__device__ __forceinline__ float bf2f(u16 u) {
  union { unsigned u; float f; } v{(unsigned)u << 16};
  return v.f;
}

__device__ __forceinline__ f32x4 mfma16(bf16x8 a, bf16x8 b, f32x4 c) {
  return __builtin_amdgcn_mfma_f32_16x16x32_bf16(a, b, c, 0, 0, 0);
}

__device__ __forceinline__ void gload_lds16(const u16* g, u16* l) {
  __builtin_amdgcn_global_load_lds(
      (const __attribute__((address_space(1))) void*)g,
      (__attribute__((address_space(3))) void*)l, 16, 0, 0);
}

// ---------------- fp32 -> bf16 conversion (batched over blockIdx.z) --------
__global__ __launch_bounds__(256) void cvt3_k(
    const float* __restrict__ a, const float* __restrict__ b,
    const float* __restrict__ c, u16* __restrict__ da,
    u16* __restrict__ db, u16* __restrict__ dc)
{
  const float* s = (blockIdx.z == 0) ? a : (blockIdx.z == 1) ? b : c;
  u16* d = (blockIdx.z == 0) ? da : (blockIdx.z == 1) ? db : dc;
  size_t i = ((size_t)blockIdx.x * 256 + threadIdx.x) * 4;
  float4 v = *(const float4*)&s[i];
  u16x4 o = { f2bf(v.x), f2bf(v.y), f2bf(v.z), f2bf(v.w) };
  *(u16x4*)&d[i] = o;
}

__global__ __launch_bounds__(256) void cvt4_k(
    const float* __restrict__ a, const float* __restrict__ b,
    const float* __restrict__ c, const float* __restrict__ e,
    u16* __restrict__ da, u16* __restrict__ db,
    u16* __restrict__ dc, u16* __restrict__ de)
{
  const float* s = (blockIdx.z == 0) ? a : (blockIdx.z == 1) ? b
                 : (blockIdx.z == 2) ? c : e;
  u16* d = (blockIdx.z == 0) ? da : (blockIdx.z == 1) ? db
         : (blockIdx.z == 2) ? dc : de;
  size_t i = ((size_t)blockIdx.x * 256 + threadIdx.x) * 4;
  float4 v = *(const float4*)&s[i];
  u16x4 o = { f2bf(v.x), f2bf(v.y), f2bf(v.z), f2bf(v.w) };
  *(u16x4*)&d[i] = o;
}

// ---------------- bf16 MFMA GEMM, 128x64 tile, BK=64, gload_lds + swizzle --
template <bool OUTBF, int NZ>
__global__ __launch_bounds__(256) void gemm_k(
    const u16* __restrict__ A0, const u16* __restrict__ A1, const u16* __restrict__ A2,
    const u16* __restrict__ W0, const u16* __restrict__ W1, const u16* __restrict__ W2,
    const float* __restrict__ b0, const float* __restrict__ b1, const float* __restrict__ b2,
    u16* __restrict__ C0, u16* __restrict__ C1, u16* __restrict__ C2,
    float* __restrict__ Cf)
{
  constexpr int BM = 128, BN = 64, BK = 64;
  __shared__ u16 Al[2][BM * BK];   // 2 x 16 KB
  __shared__ u16 Bl[2][BN * BK];   // 2 x 8 KB

  const int z = (NZ > 1) ? blockIdx.z : 0;
  const u16* Ap = (z == 0) ? A0 : (z == 1) ? A1 : A2;
  const u16* Wp = (z == 0) ? W0 : (z == 1) ? W1 : W2;
  const float* bias = (z == 0) ? b0 : (z == 1) ? b1 : b2;
  u16* Cb = (z == 0) ? C0 : (z == 1) ? C1 : C2;

  const int tid  = threadIdx.x;
  const int lane = tid & 63;
  const int w    = tid >> 6;
  const int wr = w >> 1, wc = w & 1;
  const int lg = lane >> 4, ll = lane & 15;
  const int bm = blockIdx.y * BM, bn = blockIdx.x * BN;

  auto STAGE = [&](int buf, int k0) {
#pragma unroll
    for (int i = 0; i < 4; ++i) {
      const int c = i * 256 + tid;
      const int row = c >> 3, cs = c & 7;
      const int dofs = ((cs * 16) ^ ((row & 7) << 4)) >> 1;
      gload_lds16(&Ap[(size_t)(bm + row) * GK + k0 + dofs], &Al[buf][c * 8]);
    }
#pragma unroll
    for (int i = 0; i < 2; ++i) {
      const int c = i * 256 + tid;
      const int row = c >> 3, cs = c & 7;
      const int dofs = ((cs * 16) ^ ((row & 7) << 4)) >> 1;
      gload_lds16(&Wp[(size_t)(bn + row) * GK + k0 + dofs], &Bl[buf][c * 8]);
    }
  };

  f32x4 acc[4][2] = {};

  STAGE(0, 0);
  __syncthreads();

  int cur = 0;
  constexpr int NT = GK / BK;   // 16
  for (int t = 0; t < NT; ++t) {
    if (t + 1 < NT) STAGE(cur ^ 1, (t + 1) * BK);
#pragma unroll
    for (int half = 0; half < 2; ++half) {
      bf16x8 af[4], bfr[2];
#pragma unroll
      for (int mi = 0; mi < 4; ++mi) {
        const int row = wr * 64 + mi * 16 + ll;
        af[mi] = *(const bf16x8*)&Al[cur][row * 64 +
                   (((half * 64 + lg * 16) ^ ((row & 7) << 4)) >> 1)];
      }
#pragma unroll
      for (int ni = 0; ni < 2; ++ni) {
        const int row = wc * 32 + ni * 16 + ll;
        bfr[ni] = *(const bf16x8*)&Bl[cur][row * 64 +
                   (((half * 64 + lg * 16) ^ ((row & 7) << 4)) >> 1)];
      }
#pragma unroll
      for (int mi = 0; mi < 4; ++mi)
#pragma unroll
        for (int ni = 0; ni < 2; ++ni)
          acc[mi][ni] = mfma16(af[mi], bfr[ni], acc[mi][ni]);
    }
    __syncthreads();
    cur ^= 1;
  }

#pragma unroll
  for (int ni = 0; ni < 2; ++ni) {
    const int gcol = bn + wc * 32 + ni * 16 + ll;
    const float bv = bias[gcol];
#pragma unroll
    for (int mi = 0; mi < 4; ++mi) {
      const int grow = bm + wr * 64 + mi * 16 + lg * 4;
#pragma unroll
      for (int r = 0; r < 4; ++r) {
        float v = acc[mi][ni][r] + bv;
        if (OUTBF) Cb[(size_t)(grow + r) * GN + gcol] = f2bf(v);
        else       Cf[(size_t)(grow + r) * GN + gcol] = v;
      }
    }
  }
}

// ---------------- V transpose: Vbf[b,s,h*64+d] -> Vt[(b*H+h)*64+d][s] ------
__global__ __launch_bounds__(256) void transpose_v_k(
    const u16* __restrict__ Vb, u16* __restrict__ Vt)
{
  __shared__ u16 T[64][72];
  const int tid = threadIdx.x;
  const int bh = blockIdx.y, b = bh >> 4, h = bh & 15;
  const int s0 = blockIdx.x * 64;
#pragma unroll
  for (int it = 0; it < 2; ++it) {
    int idx = tid + it * 256;
    int s = idx >> 3, dc = idx & 7;
    *(uint4*)&T[s][dc * 8] =
        *(const uint4*)&Vb[(size_t)(b * S + s0 + s) * D + h * 64 + dc * 8];
  }
  __syncthreads();
#pragma unroll
  for (int it = 0; it < 2; ++it) {
    int idx = tid + it * 256;
    int d = idx >> 3, sc = idx & 7;
    u16x8 o;
#pragma unroll
    for (int jj = 0; jj < 8; ++jj) o[jj] = T[sc * 8 + jj][d];
    *(u16x8*)&Vt[((size_t)bh * 64 + d) * S + s0 + sc * 8] = o;
  }
}

// ---------------- split-KV MFMA flash attention ----------------------------
// grid (S/64, BH, 2 splits); 4 waves x 16 q-rows. Register-diet version:
// bias folded into MFMA C-operand (dies into accumulator), V loaded per-nf
// inside PV (8 transient VGPRs), softmax in exp2 domain (native v_exp_f32).
// m/l stored in LOG2 domain; merge_k uses exp2f consistently.
__global__ __launch_bounds__(256) void attn_split_k(
    const u16* __restrict__ Qb, const u16* __restrict__ Kb,
    const u16* __restrict__ Vt, const float* __restrict__ biasS,
    const float* __restrict__ lamp, u16* __restrict__ Opart,
    float2* __restrict__ Ml)
{
  __shared__ u16 Kl[2][64 * 64];       // 2 x 8 KB, swizzled rows
  __shared__ __bf16 Pl[4][16][72];     // per-wave P, row stride 144B

  const int tid  = threadIdx.x;
  const int lane = tid & 63;
  const int w    = tid >> 6;
  const int lg = lane >> 4, ll = lane & 15;
  const int bh = blockIdx.y, b = bh >> 4, h = bh & 15;
  const int qw = blockIdx.x * 64 + w * 16;
  const int split = blockIdx.z;
  const int kvbase = split * (S / 2);  // 0 or 1024
  const float lamS = lamp[0] * 8.0f;   // lam/SCALE: bias into MFMA C-operand

  bf16x8 aQ[2];
  {
    const u16* qrow = &Qb[(size_t)(b * S + qw + ll) * D + h * 64];
    aQ[0] = *(const bf16x8*)&qrow[lg * 8];
    aQ[1] = *(const bf16x8*)&qrow[32 + lg * 8];
  }

  const u16* Kbase = &Kb[(size_t)(b * S + kvbase) * D + h * 64];
  const u16* Vbase = &Vt[(size_t)bh * 64 * S + kvbase];
  const float* Bb  = &biasS[((size_t)b * S + qw + lg * 4) * S + kvbase];

  auto STAGE_K = [&](int buf, int k0) {
#pragma unroll
    for (int i = 0; i < 2; ++i) {
      const int c   = (w * 2 + i) * 64 + lane;
      const int row = c >> 3, cs = c & 7;
      const int dofs = ((cs * 16) ^ ((row & 7) << 4)) >> 1;
      gload_lds16(&Kbase[(size_t)(k0 + row) * D + dofs],
                  &Kl[buf][(w * 2 + i) * 512]);
    }
  };

  f32x4 accO[4] = {};
  float m_r[4], l_r[4];
#pragma unroll
  for (int r = 0; r < 4; ++r) { m_r[r] = -1e30f; l_r[r] = 0.f; }

  STAGE_K(0, 0);
  __syncthreads();                     // buf0 staged

  int cur = 0;
  constexpr int NT = (S / 2) / 64;     // 16
  for (int t = 0; t < NT; ++t) {
    const int k0 = t * 64;
    if (t + 1 < NT) STAGE_K(cur ^ 1, k0 + 64);

    // ---- QK^T from LDS; bias preloaded into the C-operand ----
    f32x4 sf[4];
#pragma unroll
    for (int kf = 0; kf < 4; ++kf) {
      const int row = kf * 16 + ll;
      const u16* kr = &Kl[cur][row * 64];
      bf16x8 kb0 = *(const bf16x8*)&kr[((lg * 16) ^ ((row & 7) << 4)) >> 1];
      bf16x8 kb1 = *(const bf16x8*)&kr[((64 + lg * 16) ^ ((row & 7) << 4)) >> 1];
      f32x4 t4;
#pragma unroll
      for (int r = 0; r < 4; ++r)
        t4[r] = lamS * Bb[(size_t)r * S + k0 + kf * 16 + ll];
      t4 = mfma16(aQ[0], kb0, t4);
      t4 = mfma16(aQ[1], kb1, t4);
#pragma unroll
      for (int r = 0; r < 4; ++r) t4[r] *= SL2;    // -> log2 domain
      sf[kf] = t4;
    }

    // ---- defer-max online softmax (log2 domain, shuffle-free fast path) ---
    float pm[4];
#pragma unroll
    for (int r = 0; r < 4; ++r)
      pm[r] = fmaxf(fmaxf(sf[0][r], sf[1][r]), fmaxf(sf[2][r], sf[3][r]));
    float ex = fmaxf(fmaxf(pm[0] - m_r[0], pm[1] - m_r[1]),
                     fmaxf(pm[2] - m_r[2], pm[3] - m_r[3]));
    if (__any(ex > THR2)) {            // tile 0 always; rare after
#pragma unroll
      for (int r = 0; r < 4; ++r) {
        float tmx = pm[r];
        tmx = fmaxf(tmx, __shfl_xor(tmx, 1));
        tmx = fmaxf(tmx, __shfl_xor(tmx, 2));
        tmx = fmaxf(tmx, __shfl_xor(tmx, 4));
        tmx = fmaxf(tmx, __shfl_xor(tmx, 8));
        float nm = fmaxf(m_r[r], tmx);
        float cf = exp2f(m_r[r] - nm);
        m_r[r] = nm;
        l_r[r] *= cf;
#pragma unroll
        for (int nf = 0; nf < 4; ++nf) accO[nf][r] *= cf;
      }
    }
#pragma unroll
    for (int r = 0; r < 4; ++r) {
      float ps = 0.f;
#pragma unroll
      for (int kf = 0; kf < 4; ++kf) {
        float p = exp2f(sf[kf][r] - m_r[r]);
        Pl[w][lg * 4 + r][kf * 16 + ll] = (__bf16)p;
        ps += p;
      }
      l_r[r] += ps;                    // per-lane partial l
    }

    // ---- PV: V fragments loaded per-nf (8 transient VGPRs) ----
    bf16x8 aP0 = *(const bf16x8*)&Pl[w][ll][lg * 8];
    bf16x8 aP1 = *(const bf16x8*)&Pl[w][ll][32 + lg * 8];
#pragma unroll
    for (int nf = 0; nf < 4; ++nf) {
      const u16* vrow = &Vbase[(size_t)(nf * 16 + ll) * S + k0];
      bf16x8 v0 = *(const bf16x8*)&vrow[lg * 8];
      bf16x8 v1 = *(const bf16x8*)&vrow[32 + lg * 8];
      accO[nf] = mfma16(aP0, v0, accO[nf]);
      accO[nf] = mfma16(aP1, v1, accO[nf]);
    }

    __syncthreads();                   // next K buffer staged; Kl reads done
    cur ^= 1;
  }

  // reduce per-lane partial l across the 16-lane row groups (once)
#pragma unroll
  for (int r = 0; r < 4; ++r) {
    float tl = l_r[r];
    tl += __shfl_xor(tl, 1);
    tl += __shfl_xor(tl, 2);
    tl += __shfl_xor(tl, 4);
    tl += __shfl_xor(tl, 8);
    l_r[r] = tl;
  }

  u16* Op = Opart + (size_t)split * ((size_t)BH * S * 64);
  float2* Mlp = Ml + (size_t)split * ((size_t)BH * S);
  if (ll == 0) {
#pragma unroll
    for (int r = 0; r < 4; ++r) {
      float2 v; v.x = m_r[r]; v.y = l_r[r];   // m in log2 domain
      Mlp[(size_t)bh * S + qw + lg * 4 + r] = v;
    }
  }
#pragma unroll
  for (int nf = 0; nf < 4; ++nf)
#pragma unroll
    for (int r = 0; r < 4; ++r)
      Op[((size_t)bh * S + qw + lg * 4 + r) * 64 + nf * 16 + ll] =
          f2bf(accO[nf][r]);
}

// ---------------- merge partial attention results (log2-domain m) ----------
__global__ __launch_bounds__(256) void merge_k(
    const u16* __restrict__ Opart, const float2* __restrict__ Ml,
    u16* __restrict__ Obf)
{
  const int tid = threadIdx.x;
  const size_t row = (size_t)blockIdx.x * 32 + (tid >> 3);
  const int dc = (tid & 7) * 8;
  const float2 ml0 = Ml[row];
  const float2 ml1 = Ml[(size_t)BH * S + row];
  const float m = fmaxf(ml0.x, ml1.x);
  float c0 = exp2f(ml0.x - m), c1 = exp2f(ml1.x - m);
  const float inv = 1.0f / (c0 * ml0.y + c1 * ml1.y);
  c0 *= inv; c1 *= inv;
  u16x8 a = *(const u16x8*)&Opart[row * 64 + dc];
  u16x8 bq = *(const u16x8*)&Opart[(size_t)BH * S * 64 + row * 64 + dc];
  u16x8 o;
#pragma unroll
  for (int j = 0; j < 8; ++j)
    o[j] = f2bf(c0 * bf2f(a[j]) + c1 * bf2f(bq[j]));
  const int bh = (int)(row >> 11), q = (int)(row & 2047);
  *(u16x8*)&Obf[((size_t)((bh >> 4) * S + q)) * D + (bh & 15) * 64 + dc] = o;
}

}  // namespace

extern "C" void kernel_launch(void* const* d_in, const int* in_sizes, int n_in,
                              void* d_out, int out_size, void* d_ws, size_t ws_size,
                              hipStream_t stream)
{
  const float* query = (const float*)d_in[0];
  const float* key   = (const float*)d_in[1];
  const float* value = (const float*)d_in[2];
  const float* biasS = (const float*)d_in[3];
  const float* Wq = (const float*)d_in[4];
  const float* bq = (const float*)d_in[5];
  const float* Wk = (const float*)d_in[6];
  const float* bk = (const float*)d_in[7];
  const float* Wv = (const float*)d_in[8];
  const float* bv = (const float*)d_in[9];
  const float* Wo = (const float*)d_in[10];
  const float* bo = (const float*)d_in[11];
  const float* lam = (const float*)d_in[12];
  float* out = (float*)d_out;

  // ws layout (48 MB), regions reused once dead (see round-5 notes):
  char* ws = (char*)d_ws;
  const size_t MB = 1024 * 1024;
  u16* Xq  = (u16*)(ws + 0 * MB);
  u16* Xk  = (u16*)(ws + 8 * MB);
  u16* Xv  = (u16*)(ws + 16 * MB);
  u16* WqB = (u16*)(ws + 24 * MB);
  u16* WkB = (u16*)(ws + 26 * MB);
  u16* WvB = (u16*)(ws + 28 * MB);
  u16* WoB = (u16*)(ws + 30 * MB);
  u16* Qbf = (u16*)(ws + 32 * MB);
  u16* Kbf = (u16*)(ws + 40 * MB);
  u16* Opart = (u16*)ws;                       // [2][BH*S*64] bf16, 16 MB
  u16* Obf   = (u16*)(ws + 16 * MB);           // 8 MB (over Xv)
  u16* Vbf = (u16*)d_out;                      // 8 MB
  u16* Vt  = (u16*)d_out + (size_t)4 * MB;     // 8 MB
  float2* Ml = (float2*)d_out;                 // 1 MB (after Vbf dead)

  // 1) fp32 -> bf16
  cvt3_k<<<dim3(4096, 1, 3), 256, 0, stream>>>(query, key, value, Xq, Xk, Xv);
  cvt4_k<<<dim3(1024, 1, 4), 256, 0, stream>>>(Wq, Wk, Wv, Wo, WqB, WkB, WvB, WoB);

  // 2) fused Q,K,V projections (z=3; 1536 blocks)
  dim3 pgrid(GN / 64, GM / 128, 3);
  gemm_k<true, 3><<<pgrid, 256, 0, stream>>>(
      Xq, Xk, Xv, WqB, WkB, WvB, bq, bk, bv, Qbf, Kbf, Vbf, nullptr);

  // 3) V transpose
  transpose_v_k<<<dim3(S / 64, B * H), 256, 0, stream>>>(Vbf, Vt);

  // 4) split-KV flash attention (2048 blocks)
  attn_split_k<<<dim3(S / 64, BH, 2), 256, 0, stream>>>(
      Qbf, Kbf, Vt, biasS, lam, Opart, Ml);

  // 5) merge partials
  merge_k<<<dim3(BH * S / 32), 256, 0, stream>>>(Opart, Ml, Obf);

  // 6) output projection (fp32 out)
  dim3 ogrid(GN / 64, GM / 128, 1);
  gemm_k<false, 1><<<ogrid, 256, 0, stream>>>(
      Obf, nullptr, nullptr, WoB, nullptr, nullptr, bo, nullptr, nullptr,
      nullptr, nullptr, nullptr, out);
}